// Round 1
// baseline (587.622 us; speedup 1.0000x reference)
//
#include <hip/hip_runtime.h>
#include <hip/hip_fp16.h>

// Problem constants (from reference)
#define Nn 200000
#define Ee 6400000
#define EP 6600000            // Ee + Nn self loops
#define Hh 9
#define Ll 4
#define Gg 2000
#define Cc 2
#define JK 36                 // Ll * Hh
#define NCB ((Nn + 1023) >> 10) // 196 coarse buckets (1024 nodes each)
#define EPB 8192              // edges per phase-A block
#define NBLKA ((EP + EPB - 1) / EPB) // 806
#define NB ((Nn + 255) / 256) // 782
#define NPB 32                // nodes per k_node_agg block (oct per node)
#define NAB (Nn / NPB)        // 6250 blocks
#define CAP 3072              // staged csr entries per block (12 KB)
#define HTS (NCB + 1)         // histT row stride

union H2F { __half2 h; float f; };

// ========= CSR build: block-major multisplit + per-bucket LDS sort =========

// Phase A: per-block LDS multisplit, drained BLOCK-MAJOR (straight coalesced
// copy, no global coordination). Per-block bucket offsets -> histT row;
// global bucket totals -> ctot (196 atomics/block).
// Payload: src (18b) | dst low 10 bits << 18.
__global__ __launch_bounds__(256) void kA_scatter(
    const int* __restrict__ src, const int* __restrict__ dst,
    int* __restrict__ ctot, int* __restrict__ histT,
    unsigned* __restrict__ bucketed)
{
    __shared__ unsigned pbuf[EPB];        // 32 KB
    __shared__ int lh[NCB];
    __shared__ int s[256];
    int t = threadIdx.x;
    if (t < NCB) lh[t] = 0;
    __syncthreads();
    const int base = blockIdx.x * EPB;
    const int nseg = min(EPB, EP - base);
    // pass 1: histogram (dst only)
    for (int j = t; j < nseg; j += 256) {
        int e = base + j;
        int d = (e < Ee) ? dst[e] : (e - Ee);
        atomicAdd(&lh[d >> 10], 1);
    }
    __syncthreads();
    // exclusive scan of 196 bins
    int v = (t < NCB) ? lh[t] : 0;
    s[t] = v; __syncthreads();
    for (int off = 1; off < 256; off <<= 1) {
        int u = (t >= off) ? s[t - off] : 0;
        __syncthreads();
        s[t] += u;
        __syncthreads();
    }
    int* hrow = histT + (size_t)blockIdx.x * HTS;
    if (t < NCB) {
        int ex = s[t] - v;
        lh[t] = ex;                        // LDS cursor
        hrow[t] = ex;                      // run starts for kB
        if (v) atomicAdd(&ctot[t], v);
    }
    if (t == 0) hrow[NCB] = nseg;
    __syncthreads();
    // pass 2: scatter into LDS (bucket-ordered within block)
    for (int j = t; j < nseg; j += 256) {
        int e = base + j;
        int sv, d;
        if (e < Ee) { sv = src[e]; d = dst[e]; } else { sv = e - Ee; d = sv; }
        int pos = atomicAdd(&lh[d >> 10], 1);
        pbuf[pos] = (unsigned)sv | ((unsigned)(d & 1023) << 18);
    }
    __syncthreads();
    // pass 3: straight coalesced drain, block-major
    for (int j = t; j < nseg; j += 256)
        bucketed[base + j] = pbuf[j];
}

// Scan coarse totals -> cbase.
__global__ __launch_bounds__(256) void k_scan(
    const int* __restrict__ ctot, int* __restrict__ cbase,
    int* __restrict__ row_ptr)
{
    __shared__ int s[256];
    int t = threadIdx.x;
    int v = (t < NCB) ? ctot[t] : 0;
    s[t] = v; __syncthreads();
    for (int off = 1; off < 256; off <<= 1) {
        int u = (t >= off) ? s[t - off] : 0;
        __syncthreads();
        s[t] += u;
        __syncthreads();
    }
    if (t < NCB) cbase[t] = s[t] - v;
    if (t == 0) { cbase[NCB] = EP; row_ptr[Nn] = EP; }
}

// Phase B: ONE 1024-thread block per coarse bucket. Its entries live in 806
// short runs (block-major regions, bounds from histT). Two passes:
// 1024-bin hist -> scan -> scatter into private csr window. row_ptr analytic.
__global__ __launch_bounds__(1024) void kB_csr(
    const unsigned* __restrict__ bucketed, const int* __restrict__ histT,
    const int* __restrict__ cbase, int* __restrict__ row_ptr,
    int* __restrict__ csr_src)
{
    __shared__ int bh[1024];
    __shared__ int cur[1024];
    const int k = blockIdx.x;
    const int t = threadIdx.x;
    const int w = t >> 6, lane = t & 63;  // 16 waves
    bh[t] = 0;
    __syncthreads();
    for (int b = w; b < NBLKA; b += 16) {
        const int* hrow = histT + (size_t)b * HTS;
        int s0 = hrow[k], s1 = hrow[k + 1];   // same addr all lanes: broadcast
        int rb = b * EPB;
        for (int j = s0 + lane; j < s1; j += 64)
            atomicAdd(&bh[(bucketed[rb + j] >> 18) & 1023], 1);
    }
    __syncthreads();
    int v = bh[t];
    for (int off = 1; off < 1024; off <<= 1) {
        int u = (t >= off) ? bh[t - off] : 0;
        __syncthreads();
        bh[t] += u;
        __syncthreads();
    }
    int pos0 = cbase[k] + bh[t] - v;      // exclusive scan
    int node = (k << 10) + t;
    if (node < Nn) row_ptr[node] = pos0;
    cur[t] = pos0;
    __syncthreads();
    for (int b = w; b < NBLKA; b += 16) {
        const int* hrow = histT + (size_t)b * HTS;
        int s0 = hrow[k], s1 = hrow[k + 1];
        int rb = b * EPB;
        for (int j = s0 + lane; j < s1; j += 64) {
            unsigned p = bucketed[rb + j];
            int pos = atomicAdd(&cur[(p >> 18) & 1023], 1);
            csr_src[pos] = (int)(p & 0x3FFFFu);
        }
    }
}

// ============ per-layer kernels ============

// Gather-table layout (L2-resident: 3.6 MB total < 4 MB per-XCD L2):
//   A[i]  : 16 B  = h0..h7 as 4x half2              (3.2 MB)
//   Bh[i] :  2 B  = h8 as half                      (0.4 MB)
//   D[i]  :  4 B  = alpha_d fp32 (read per NODE)    (0.8 MB)
// alpha_s is NOT stored: it is recomputed per edge from the gathered fp16 h
// (9 FMAs; VALU has ~5x headroom vs the gather pipe).
__global__ __launch_bounds__(256) void k_transform(
    const float* __restrict__ xin, int xstride,
    const float* __restrict__ Wl,
    const float* __restrict__ adst,
    float4* __restrict__ A, __half* __restrict__ Bh, float* __restrict__ D)
{
    int i = blockIdx.x * blockDim.x + threadIdx.x;
    if (i >= Nn) return;
    const float* xp = xin + (size_t)i * xstride;
    float xi[Hh];
#pragma unroll
    for (int k = 0; k < Hh; ++k) xi[k] = xp[k];
    float hv[Hh];
#pragma unroll
    for (int j = 0; j < Hh; ++j) {
        float s = 0.f;
#pragma unroll
        for (int k = 0; k < Hh; ++k) s += xi[k] * Wl[k * Hh + j];
        hv[j] = s;
    }
    float ad = 0.f;
#pragma unroll
    for (int j = 0; j < Hh; ++j) ad += hv[j] * adst[j];
    H2F u01, u23, u45, u67;
    u01.h = __floats2half2_rn(hv[0], hv[1]);
    u23.h = __floats2half2_rn(hv[2], hv[3]);
    u45.h = __floats2half2_rn(hv[4], hv[5]);
    u67.h = __floats2half2_rn(hv[6], hv[7]);
    A[i] = make_float4(u01.f, u23.f, u45.f, u67.f);
    Bh[i] = __float2half(hv[8]);
    D[i] = ad;
}

// Oct-per-node gather with LDS-staged CSR, 2-deep software-pipelined gathers.
// Single-pass softmax: |logits| << 88 so exp never overflows; ratio exact.
__global__ __launch_bounds__(256) void k_node_agg(
    const int* __restrict__ rp, const int* __restrict__ csr,
    const float4* __restrict__ A, const __half* __restrict__ Bh,
    const float* __restrict__ D, const float* __restrict__ asrc,
    const float* __restrict__ biasl,
    float* __restrict__ jk, int l)
{
    __shared__ int scsr[CAP];
    __shared__ int srp[NPB + 1];
    const int nbase = blockIdx.x * NPB;
    const int t = threadIdx.x;
    if (t <= NPB) srp[t] = rp[nbase + t];   // nbase+NPB <= Nn; rp[Nn] = EP
    __syncthreads();
    const int beg_blk = srp[0];
    const int nseg = srp[NPB] - beg_blk;
    const bool use_lds = (nseg <= CAP);
    if (use_lds)
        for (int j = t; j < nseg; j += 256)
            scsr[j] = __builtin_nontemporal_load(csr + beg_blk + j); // streamed
    __syncthreads();

    // att_src for this layer (uniform -> SGPRs)
    const float s0 = asrc[0], s1 = asrc[1], s2 = asrc[2], s3 = asrc[3],
                s4 = asrc[4], s5 = asrc[5], s6 = asrc[6], s7 = asrc[7],
                s8 = asrc[8];

    const int ni = t >> 3;          // node within block
    const int q  = t & 7;           // lane within oct
    const int i  = nbase + ni;
    const float c = D[i];           // own alpha_d (fp32, once per node)
    float a0=0,a1=0,a2=0,a3=0,a4=0,a5=0,a6=0,a7=0,a8=0,den=0;
    if (use_lds) {
        int idx = srp[ni] - beg_blk + q;
        const int iend = srp[ni + 1] - beg_blk;
        int s = (idx < iend) ? scsr[idx] : 0;
        float4 F = A[s];                    // prime the pipeline (s=0 is valid)
        __half hb = Bh[s];
        while (idx < iend) {
            int nidx = idx + 8;
            int sn = (nidx < iend) ? scsr[nidx] : 0;
            float4 Fn = A[sn];              // issue next gather BEFORE using F
            __half hbn = Bh[sn];
            H2F u; float2 p;
            u.f = F.x; p = __half22float2(u.h); float x0 = p.x, x1 = p.y;
            u.f = F.y; p = __half22float2(u.h); float x2 = p.x, x3 = p.y;
            u.f = F.z; p = __half22float2(u.h); float x4 = p.x, x5 = p.y;
            u.f = F.w; p = __half22float2(u.h); float x6 = p.x, x7 = p.y;
            float x8 = __half2float(hb);
            float as = x0*s0 + x1*s1 + x2*s2 + x3*s3 + x4*s4
                     + x5*s5 + x6*s6 + x7*s7 + x8*s8;
            float lg = as + c;
            lg = lg > 0.f ? lg : 0.2f * lg;            // leaky_relu(0.2)
            float w = __expf(lg);
            a0 += w*x0; a1 += w*x1; a2 += w*x2; a3 += w*x3; a4 += w*x4;
            a5 += w*x5; a6 += w*x6; a7 += w*x7; a8 += w*x8;
            den += w;
            F = Fn; hb = hbn; idx = nidx;
        }
    } else {
        for (int e = srp[ni] + q; e < srp[ni + 1]; e += 8) {
            int s = csr[e];
            float4 F = A[s];
            __half hb = Bh[s];
            H2F u; float2 p;
            u.f = F.x; p = __half22float2(u.h); float x0 = p.x, x1 = p.y;
            u.f = F.y; p = __half22float2(u.h); float x2 = p.x, x3 = p.y;
            u.f = F.z; p = __half22float2(u.h); float x4 = p.x, x5 = p.y;
            u.f = F.w; p = __half22float2(u.h); float x6 = p.x, x7 = p.y;
            float x8 = __half2float(hb);
            float as = x0*s0 + x1*s1 + x2*s2 + x3*s3 + x4*s4
                     + x5*s5 + x6*s6 + x7*s7 + x8*s8;
            float lg = as + c;
            lg = lg > 0.f ? lg : 0.2f * lg;
            float w = __expf(lg);
            a0 += w*x0; a1 += w*x1; a2 += w*x2; a3 += w*x3; a4 += w*x4;
            a5 += w*x5; a6 += w*x6; a7 += w*x7; a8 += w*x8;
            den += w;
        }
    }
#pragma unroll
    for (int m = 1; m <= 4; m <<= 1) {
        a0 += __shfl_xor(a0, m); a1 += __shfl_xor(a1, m);
        a2 += __shfl_xor(a2, m); a3 += __shfl_xor(a3, m);
        a4 += __shfl_xor(a4, m); a5 += __shfl_xor(a5, m);
        a6 += __shfl_xor(a6, m); a7 += __shfl_xor(a7, m);
        a8 += __shfl_xor(a8, m); den += __shfl_xor(den, m);
    }
    if (q == 0) {
        float inv = 1.f / den;          // den >= 1 (self-loop term)
        float* jp = jk + (size_t)i * JK + l * Hh;
        float o;
        o = fmaxf(a0*inv + biasl[0], 0.f); __builtin_nontemporal_store(o, jp + 0);
        o = fmaxf(a1*inv + biasl[1], 0.f); __builtin_nontemporal_store(o, jp + 1);
        o = fmaxf(a2*inv + biasl[2], 0.f); __builtin_nontemporal_store(o, jp + 2);
        o = fmaxf(a3*inv + biasl[3], 0.f); __builtin_nontemporal_store(o, jp + 3);
        o = fmaxf(a4*inv + biasl[4], 0.f); __builtin_nontemporal_store(o, jp + 4);
        o = fmaxf(a5*inv + biasl[5], 0.f); __builtin_nontemporal_store(o, jp + 5);
        o = fmaxf(a6*inv + biasl[6], 0.f); __builtin_nontemporal_store(o, jp + 6);
        o = fmaxf(a7*inv + biasl[7], 0.f); __builtin_nontemporal_store(o, jp + 7);
        o = fmaxf(a8*inv + biasl[8], 0.f); __builtin_nontemporal_store(o, jp + 8);
    }
}

// ============ pool + fc ============

// batch is sorted -> graphs are contiguous node ranges. Build range starts.
__global__ __launch_bounds__(256) void k_graph_ptr(
    const int* __restrict__ batch, int* __restrict__ gp)
{
    int i = blockIdx.x * 256 + threadIdx.x;
    if (i >= Nn) return;
    int b = batch[i];
    if (i == 0) {
        for (int g = 0; g <= b; ++g) gp[g] = 0;
    } else {
        int pb = batch[i - 1];
        for (int g = pb + 1; g <= b; ++g) gp[g] = i;
    }
    if (i == Nn - 1) {
        for (int g = b + 1; g <= Gg; ++g) gp[g] = Nn;
    }
}

// Segmented max, one thread per (graph, col). Post-relu values >= 0 and
// init 0 reproduces the isfinite->0 guard for empty graphs.
__global__ __launch_bounds__(256) void k_pool_seg(
    const float* __restrict__ jk, const int* __restrict__ gp,
    float* __restrict__ pooled)
{
    int t = blockIdx.x * 256 + threadIdx.x;
    if (t >= Gg * JK) return;
    int g = t / JK, col = t - g * JK;
    int beg = gp[g], end = gp[g + 1];
    float m = 0.f;
    for (int i = beg; i < end; ++i)
        m = fmaxf(m, jk[(size_t)i * JK + col]);
    pooled[t] = m;
}

__global__ __launch_bounds__(256) void k_fc(
    const float* __restrict__ pooled, const float* __restrict__ fcw,
    const float* __restrict__ fcb, float* __restrict__ out)
{
    int t = blockIdx.x * blockDim.x + threadIdx.x;
    if (t >= Gg * Cc) return;
    int g = t / Cc, c = t - g * Cc;
    float s = fcb[c];
    const float* pp = pooled + (size_t)g * JK;
#pragma unroll
    for (int j = 0; j < JK; ++j) s += pp[j] * fcw[j * Cc + c];
    out[t] = s;
}

extern "C" void kernel_launch(void* const* d_in, const int* in_sizes, int n_in,
                              void* d_out, int out_size, void* d_ws, size_t ws_size,
                              hipStream_t stream) {
    const float* x      = (const float*)d_in[0];   // [N,9]
    const int*   ei     = (const int*)d_in[1];     // [2,E]: src row then dst row
    const int*   batch  = (const int*)d_in[2];     // [N] sorted
    const float* W      = (const float*)d_in[3];   // [L,9,9]
    const float* a_src  = (const float*)d_in[4];   // [L,9]
    const float* a_dst  = (const float*)d_in[5];   // [L,9]
    const float* bias   = (const float*)d_in[6];   // [L,9]
    const float* fc_w   = (const float*)d_in[7];   // [36,2]
    const float* fc_b   = (const float*)d_in[8];   // [2]
    float* out = (float*)d_out;

    // Workspace layout (~61 MB live). histT aliases A, bucketed aliases jk —
    // both dead before A/jk are first written (same-stream ordering).
    float* ws        = (float*)d_ws;
    float4* A        = (float4*)ws;                       // Nn*16B (3.2MB)
    __half* Bh       = (__half*)(ws + (size_t)Nn * 4);    // Nn*2B  (0.4MB)
    float* D         = (float*)((char*)Bh + (size_t)Nn * sizeof(__half)); // Nn*4B
    float* jk        = D + Nn;                            // Nn*JK (28.8MB)
    float* pooled    = jk + (size_t)Nn * JK;              // Gg*JK
    int* row_ptr     = (int*)(pooled + (size_t)Gg * JK);  // Nn+1
    int* gp          = row_ptr + Nn + 1;                  // Gg+1
    int* ctot        = gp + Gg + 1;                       // NCB
    int* cbase       = ctot + NCB;                        // NCB+1
    int* csr_src     = cbase + NCB + 1;                   // EP (26.4MB)
    int* histT       = (int*)ws;                          // aliases A (0.64MB)
    unsigned* bucketed = (unsigned*)jk;                   // EP alias (26.4MB)

    const int* srcp = ei;
    const int* dstp = ei + Ee;

    // CSR build (edge structure is layer-invariant)
    hipMemsetAsync(ctot, 0, NCB * sizeof(int), stream);
    kA_scatter<<<NBLKA, 256, 0, stream>>>(srcp, dstp, ctot, histT, bucketed);
    k_scan    <<<1, 256, 0, stream>>>(ctot, cbase, row_ptr);
    kB_csr    <<<NCB, 1024, 0, stream>>>(bucketed, histT, cbase, row_ptr, csr_src);

    for (int l = 0; l < Ll; ++l) {
        const float* xin = (l == 0) ? x : (jk + (size_t)(l - 1) * Hh);
        int xstride      = (l == 0) ? Hh : JK;
        k_transform<<<NB, 256, 0, stream>>>(xin, xstride, W + l * Hh * Hh,
                                            a_dst + l * Hh, A, Bh, D);
        k_node_agg<<<NAB, 256, 0, stream>>>(row_ptr, csr_src, A, Bh, D,
                                            a_src + l * Hh, bias + l * Hh, jk, l);
    }
    k_graph_ptr<<<NB, 256, 0, stream>>>(batch, gp);
    k_pool_seg<<<(Gg * JK + 255) / 256, 256, 0, stream>>>(jk, gp, pooled);
    k_fc<<<(Gg * Cc + 255) / 256, 256, 0, stream>>>(pooled, fc_w, fc_b, out);
}